// Round 4
// baseline (992.738 us; speedup 1.0000x reference)
//
#include <hip/hip_runtime.h>
#include <cstdint>

// Problem dims
#define DB   8
#define DL   4096
#define DD   768
#define DDI  1536
#define DN   64
#define DH   24
#define DP   64
#define DCD  1664
#define DIPD 3224
#define BL   (DB*DL)      // 32768 tokens
#define NCH  64           // chunks (L/64)
#define ZLD  3200         // zx row stride (z 1536 | xBC 1664)

typedef __attribute__((ext_vector_type(8))) short bf16x8;
typedef __attribute__((ext_vector_type(4))) float f32x4;

__device__ __forceinline__ unsigned short f2bf(float f){
  unsigned u = __float_as_uint(f);
  u += 0x7FFFu + ((u >> 16) & 1u);
  return (unsigned short)(u >> 16);
}
__device__ __forceinline__ float bf2f(unsigned short s){
  return __uint_as_float(((unsigned)s) << 16);
}
__device__ __forceinline__ unsigned pack2(unsigned short a, unsigned short b){
  return (unsigned)a | ((unsigned)b << 16);
}
__device__ __forceinline__ void pack16(const unsigned short* ov, uint4& u0, uint4& u1){
  u0.x = pack2(ov[0],ov[1]);  u0.y = pack2(ov[2],ov[3]);
  u0.z = pack2(ov[4],ov[5]);  u0.w = pack2(ov[6],ov[7]);
  u1.x = pack2(ov[8],ov[9]);  u1.y = pack2(ov[10],ov[11]);
  u1.z = pack2(ov[12],ov[13]); u1.w = pack2(ov[14],ov[15]);
}
__device__ __forceinline__ void async16(void* lds, const void* g){
  __builtin_amdgcn_global_load_lds((const __attribute__((address_space(1))) unsigned*)g,
                                   (__attribute__((address_space(3))) unsigned*)lds, 16, 0, 0);
}
__device__ __forceinline__ float softplusf(float v){
  return v > 15.f ? v : log1pf(expf(v));
}
__device__ __forceinline__ float siluf(float v){
  return v / (1.f + expf(-v));
}

// ---------------- K0: fp32 -> bf16 weight conversion (Win, Wout) ----------------
__global__ void cvt_kernel(const float* __restrict__ win, const float* __restrict__ wout,
                           unsigned short* __restrict__ winb, unsigned short* __restrict__ woutb){
  int i = blockIdx.x*256 + threadIdx.x;
  const int WN = (DIPD*DD)/4;   // 619008
  const int ON = (DD*DDI)/4;    // 294912
  if (i < WN){
    float4 v = ((const float4*)win)[i];
    uint2 o; o.x = pack2(f2bf(v.x), f2bf(v.y)); o.y = pack2(f2bf(v.z), f2bf(v.w));
    ((uint2*)winb)[i] = o;
  } else if (i < WN+ON){
    int j = i - WN;
    float4 v = ((const float4*)wout)[j];
    uint2 o; o.x = pack2(f2bf(v.x), f2bf(v.y)); o.y = pack2(f2bf(v.z), f2bf(v.w));
    ((uint2*)woutb)[j] = o;
  }
}

// ---------------- K1: LayerNorm -> xn (bf16) ----------------
__global__ void ln_kernel(const float* __restrict__ x, const float* __restrict__ w,
                          const float* __restrict__ bb, unsigned short* __restrict__ xn){
  int row = blockIdx.x; int tid = threadIdx.x;
  const float* xr = x + (size_t)row*DD;
  float v0=xr[tid], v1=xr[tid+256], v2=xr[tid+512];
  float s = v0+v1+v2;
  float s2 = v0*v0+v1*v1+v2*v2;
  for (int off=32; off>0; off>>=1){ s += __shfl_down(s, off); s2 += __shfl_down(s2, off); }
  __shared__ float red[10];
  int wv = tid>>6;
  if ((tid&63)==0){ red[wv]=s; red[4+wv]=s2; }
  __syncthreads();
  if (tid==0){
    float a=red[0]+red[1]+red[2]+red[3];
    float c=red[4]+red[5]+red[6]+red[7];
    red[8]=a*(1.f/768.f); red[9]=c*(1.f/768.f);
  }
  __syncthreads();
  float mu = red[8];
  float inv = rsqrtf(red[9]-mu*mu + 1e-5f);
  unsigned short* o = xn + (size_t)row*DD;
  o[tid]     = f2bf((v0-mu)*inv*w[tid]     + bb[tid]);
  o[tid+256] = f2bf((v1-mu)*inv*w[tid+256] + bb[tid+256]);
  o[tid+512] = f2bf((v2-mu)*inv*w[tid+512] + bb[tid+512]);
}

// ---------------- K2: bf16 MFMA GEMM — 256x128 block, 128x64 wave tile, BK=32 ----------------
// Round-4 theory: round-3 counters show the K-loop is LDS-read/staging THROUGHPUT bound
// (973 cyc/CU/K-iter ≈ ds_read_b128 time incl. 8-way conflicts; MFMA needs only ~307).
// Both costs scale with bytes/FLOP, so:
//  - wave tile 64x64 -> 128x64: FLOP per LDS-read byte 32 -> 42.7 (-25% LDS traffic)
//  - block 128x128 -> 256x128: FLOP per staged byte +37%
//  - 16B-chunk XOR swizzle (c ^= (row>>2)&3): fragment reads go 8-way -> uniform 2-way
//    (free, m136). global_load_lds dest stays LINEAR; the inverse permutation is applied
//    to the per-lane GLOBAL source chunk (rule #21): gc = (lane&3)^(lane>>4); read side
//    uses the lane-constant cswz = ((lane>>4)^((lane>>2)&3))*8.
//  - acc 32x f32x4 (~200 unified regs) -> 2 blocks/CU; fine for a throughput-bound loop.
// MODE 1: zxbcdt = xn @ Win^T; cols [0,3200)->zx bf16 (stride ZLD), cols [3200,3224)->softplus(+dt_bias)->dt f32
// MODE 2: out = A(lda) @ Wout^T + x (fp32 store, nontemporal)
template<int MODE>
__launch_bounds__(256,2)
__global__ void gemm_kernel(const unsigned short* __restrict__ A,
                            const unsigned short* __restrict__ Bw,
                            int K, int lda, int Brows, int nbn,
                            unsigned short* __restrict__ zx, float* __restrict__ dtbuf,
                            const float* __restrict__ dt_bias,
                            const float* __restrict__ xres, float* __restrict__ outp)
{
  __shared__ __align__(16) unsigned short As[256*32];   // 16 KiB
  __shared__ __align__(16) unsigned short Bs[128*32];   //  8 KiB
  int tid = threadIdx.x; int lane = tid&63; int wv = tid>>6;
  // --- XCD-aware remap (nwg % 8 == 0 for both call sites), bn-fast for A-panel L2 reuse ---
  int nwg  = gridDim.x;
  int orig = blockIdx.x;
  int q    = nwg >> 3;
  int wgid = (orig & 7)*q + (orig >> 3);
  int bm = wgid / nbn, bn = wgid % nbn;

  // ---- staging (pre-swizzled global source chunk; linear LDS dest) ----
  const int gc = ((lane&3) ^ (lane>>4)) * 8;   // source element offset within 32-elem row
  const int sr = wv*16 + (lane>>2);            // local staging row (0..63 across waves)
  const unsigned short* pa = A + (size_t)(bm*256 + sr)*lda + gc;
  int rb0 = bn*128 + sr;       if (rb0 > Brows-1) rb0 = Brows-1;
  int rb1 = bn*128 + sr + 64;  if (rb1 > Brows-1) rb1 = Brows-1;
  const unsigned short* pb0 = Bw + (size_t)rb0*K + gc;
  const unsigned short* pb1 = Bw + (size_t)rb1*K + gc;
  unsigned short* da = &As[(wv*16)*32];        // wave-uniform dests
  unsigned short* db = &Bs[(wv*16)*32];

  // ---- fragment read addressing (swizzled chunk is lane-constant) ----
  const int cswz = ((lane>>4) ^ ((lane>>2)&3)) * 8;
  const int am0 = (wv&1)*128 + (lane&15);      // wave M-quadrant row base
  const int bq0 = (wv>>1)*64 + (lane&15);      // wave N-quadrant row base

  f32x4 acc[8][4];
  #pragma unroll
  for (int i=0;i<8;i++)
    #pragma unroll
    for (int j=0;j<4;j++) acc[i][j] = (f32x4){0.f,0.f,0.f,0.f};

  for (int k0=0; k0<K; k0+=32){
    async16(da,          pa);
    async16(da +  64*32, pa +  (size_t)64*lda);
    async16(da + 128*32, pa + (size_t)128*lda);
    async16(da + 192*32, pa + (size_t)192*lda);
    async16(db,          pb0);
    async16(db +  64*32, pb1);
    pa += 32; pb0 += 32; pb1 += 32;
    __syncthreads();
    bf16x8 af[8], bfr[4];
    #pragma unroll
    for (int j=0;j<4;j++) bfr[j] = *(const bf16x8*)&Bs[(bq0 + j*16)*32 + cswz];
    #pragma unroll
    for (int i=0;i<8;i++) af[i]  = *(const bf16x8*)&As[(am0 + i*16)*32 + cswz];
    #pragma unroll
    for (int i=0;i<8;i++)
      #pragma unroll
      for (int j=0;j<4;j++)
        acc[i][j] = __builtin_amdgcn_mfma_f32_16x16x32_bf16(af[i], bfr[j], acc[i][j], 0, 0, 0);
    __syncthreads();
  }

  int mrow0 = bm*256 + (wv&1)*128 + (lane>>4)*4;
  int ncol0 = bn*128 + (wv>>1)*64 + (lane&15);
  #pragma unroll
  for (int i=0;i<8;i++){
    #pragma unroll
    for (int j=0;j<4;j++){
      int col = ncol0 + j*16;
      #pragma unroll
      for (int r=0;r<4;r++){
        int row = mrow0 + i*16 + r;
        float v = acc[i][j][r];
        if (MODE == 1){
          if (col < 3200){
            zx[(size_t)row*ZLD + col] = f2bf(v);
          } else {
            int cc = col - 3200;
            if (cc < DH) dtbuf[(size_t)row*DH + cc] = softplusf(v + dt_bias[cc]);
          }
        } else {
          float xr = __builtin_nontemporal_load(&xres[(size_t)row*DD + col]);
          __builtin_nontemporal_store(v + xr, &outp[(size_t)row*DD + col]);
        }
      }
    }
  }
}

// ---------------- K3: depthwise causal conv K=4 + bias + silu ----------------
// bx<24 -> xsT[b][h=bx][chunk][p][t]; bx==24 -> Bn (b,l,n) + BT (b,chunk,n,t); bx==25 -> Cn (b,l,n)
__global__ void conv_kernel(const unsigned short* __restrict__ zx,
                            const float* __restrict__ cw, const float* __restrict__ cb,
                            unsigned short* __restrict__ xsT, unsigned short* __restrict__ Bn,
                            unsigned short* __restrict__ Cn, unsigned short* __restrict__ BT)
{
  int bx = blockIdx.x, by = blockIdx.y, b = blockIdx.z;
  int tid = threadIdx.x;
  __shared__ __align__(16) unsigned short in_s[67*64];
  int l0 = by*64;
  for (int idx = tid; idx < 67*8; idx += 256){
    int r = idx >> 3, c8 = idx & 7;
    int l = l0 - 3 + r;
    uint4 v = make_uint4(0u,0u,0u,0u);
    if (l >= 0) v = *(const uint4*)&zx[(size_t)(b*DL + l)*ZLD + 1536 + bx*64 + c8*8];
    *(uint4*)&in_s[r*64 + c8*8] = v;
  }
  __syncthreads();
  int c = tid & 63, li = tid >> 6;
  int chn = bx*64 + c;
  float w0=cw[chn*4+0], w1=cw[chn*4+1], w2=cw[chn*4+2], w3=cw[chn*4+3];
  float bias = cb[chn];
  unsigned short ov[16];
  #pragma unroll
  for (int q=0;q<16;q++){
    int t = li*16 + q;
    float a = bias
      + w0*bf2f(in_s[(t+0)*64 + c])
      + w1*bf2f(in_s[(t+1)*64 + c])
      + w2*bf2f(in_s[(t+2)*64 + c])
      + w3*bf2f(in_s[(t+3)*64 + c]);
    ov[q] = f2bf(siluf(a));
  }
  if (bx < 24){
    size_t base = ((((size_t)(b*DH + bx))*64 + by)*64 + c)*64 + li*16;
    uint4 u0,u1; pack16(ov,u0,u1);
    *(uint4*)&xsT[base]   = u0;
    *(uint4*)&xsT[base+8] = u1;
  } else if (bx == 24){
    #pragma unroll
    for (int q=0;q<16;q++)
      Bn[(size_t)(b*DL + l0 + li*16 + q)*64 + c] = ov[q];
    size_t bt = (((size_t)(b*64 + by))*64 + c)*64 + li*16;
    uint4 u0,u1; pack16(ov,u0,u1);
    *(uint4*)&BT[bt]   = u0;
    *(uint4*)&BT[bt+8] = u1;
  } else {
    #pragma unroll
    for (int q=0;q<16;q++)
      Cn[(size_t)(b*DL + l0 + li*16 + q)*64 + c] = ov[q];
  }
}

// ---------------- K4: per-(b,h,chunk) logdA cumsum (fp32) ----------------
__global__ void cum_kernel(const float* __restrict__ dt, const float* __restrict__ A_log,
                           float* __restrict__ cum, float* __restrict__ dtT)
{
  int tid = threadIdx.x; int lane = tid&63; int wv = tid>>6;
  int idx = blockIdx.x*4 + wv;            // (b*24+h)*64 + ch
  int b = idx / 1536; int r = idx % 1536; int h = r >> 6; int chk = r & 63;
  float dv = dt[((size_t)(b*DL + chk*64 + lane))*DH + h];
  float ld = -dv * expf(A_log[h]);
  for (int off=1; off<64; off<<=1){
    float v = __shfl_up(ld, off);
    if (lane >= off) ld += v;
  }
  size_t cb = (size_t)idx*64;
  cum[cb + lane] = ld;
  dtT[cb + lane] = dv;
}

// ---------------- K5: phase A — per-chunk state contribution S = Xw^T @ B ----------------
__global__ void phaseA_kernel(const unsigned short* __restrict__ xsT,
                              const unsigned short* __restrict__ BT,
                              const float* __restrict__ cum, const float* __restrict__ dtT,
                              unsigned short* __restrict__ S)
{
  int chk = blockIdx.x, h = blockIdx.y, b = blockIdx.z;
  int tid = threadIdx.x, lane = tid&63, wv = tid>>6;
  __shared__ __align__(16) unsigned short Xw[64*72];
  __shared__ __align__(16) unsigned short Bl[64*72];
  __shared__ float wl[64];
  size_t cbase = ((size_t)((b*DH + h)*64 + chk))*64;
  if (tid < 64){
    float cv  = cum[cbase + tid];
    float c63 = cum[cbase + 63];
    wl[tid] = expf(c63 - cv) * dtT[cbase + tid];
  }
  __syncthreads();
  size_t xbase = cbase*64;
  size_t btb = ((size_t)(b*64 + chk))*4096;
  {
    int p = tid>>2, t16 = (tid&3)*16;
    #pragma unroll
    for (int half=0; half<2; half++){
      int t8 = t16 + half*8;
      uint4 xv = *(const uint4*)&xsT[xbase + p*64 + t8];
      const unsigned short* xp = (const unsigned short*)&xv;
      unsigned short ow[8];
      #pragma unroll
      for (int j=0;j<8;j++) ow[j] = f2bf(bf2f(xp[j]) * wl[t8+j]);
      uint4 u0; u0.x=pack2(ow[0],ow[1]); u0.y=pack2(ow[2],ow[3]); u0.z=pack2(ow[4],ow[5]); u0.w=pack2(ow[6],ow[7]);
      *(uint4*)&Xw[p*72 + t8] = u0;
      *(uint4*)&Bl[p*72 + t8] = *(const uint4*)&BT[btb + p*64 + t8];
    }
  }
  __syncthreads();
  int p0 = (wv&1)*32, n0 = (wv>>1)*32;
  int ml = lane&15, ko = (lane>>4)*8;
  f32x4 acc[2][2];
  #pragma unroll
  for (int i=0;i<2;i++)
    #pragma unroll
    for (int j=0;j<2;j++) acc[i][j] = (f32x4){0.f,0.f,0.f,0.f};
  #pragma unroll
  for (int ks=0; ks<64; ks+=32){
    bf16x8 a0 = *(const bf16x8*)&Xw[(p0+ml)*72    + ks + ko];
    bf16x8 a1 = *(const bf16x8*)&Xw[(p0+16+ml)*72 + ks + ko];
    bf16x8 b0 = *(const bf16x8*)&Bl[(n0+ml)*72    + ks + ko];
    bf16x8 b1 = *(const bf16x8*)&Bl[(n0+16+ml)*72 + ks + ko];
    acc[0][0] = __builtin_amdgcn_mfma_f32_16x16x32_bf16(a0,b0,acc[0][0],0,0,0);
    acc[0][1] = __builtin_amdgcn_mfma_f32_16x16x32_bf16(a0,b1,acc[0][1],0,0,0);
    acc[1][0] = __builtin_amdgcn_mfma_f32_16x16x32_bf16(a1,b0,acc[1][0],0,0,0);
    acc[1][1] = __builtin_amdgcn_mfma_f32_16x16x32_bf16(a1,b1,acc[1][1],0,0,0);
  }
  #pragma unroll
  for (int i=0;i<2;i++){
    #pragma unroll
    for (int j=0;j<2;j++){
      int n = n0 + j*16 + ml;
      int pr = p0 + i*16 + (lane>>4)*4;
      #pragma unroll
      for (int r=0;r<4;r++)
        S[xbase + (size_t)(pr+r)*64 + n] = f2bf(acc[i][j][r]);
    }
  }
}

// ---------------- K6: phase B — sequential cross-chunk state recurrence (IN PLACE: hinit==S) ----------------
// Depth-4 software pipeline: the chunk-(k) update consumes data loaded 4 iterations
// earlier (~4x iteration body >> L3 latency), instead of stalling ~500cy per chunk.
// Named registers only (rule #20: runtime-indexed arrays spill to scratch).
__global__ void phaseB_kernel(unsigned short* __restrict__ S,   // becomes hinit
                              const float* __restrict__ cum)
{
  int bh = blockIdx.x; int tid = threadIdx.x;
  size_t base = (size_t)bh * (64*4096) + (size_t)tid*16;
  size_t cb = (size_t)bh * 4096;
  float st[16];
  #pragma unroll
  for (int q=0;q<16;q++) st[q] = 0.f;
  uint4 pa0 = *(const uint4*)&S[base];            uint4 pb0 = *(const uint4*)&S[base + 8];
  uint4 pa1 = *(const uint4*)&S[base + 4096];     uint4 pb1 = *(const uint4*)&S[base + 4096 + 8];
  uint4 pa2 = *(const uint4*)&S[base + 2*4096];   uint4 pb2 = *(const uint4*)&S[base + 2*4096 + 8];
  uint4 pa3 = *(const uint4*)&S[base + 3*4096];   uint4 pb3 = *(const uint4*)&S[base + 3*4096 + 8];
  for (int c4 = 0; c4 < 16; ++c4){
    size_t off = base + (size_t)c4*(4*4096);
#define PB_STEP(PA,PB,IDX)                                                       \
    {                                                                            \
      unsigned short ov[16];                                                     \
      _Pragma("unroll")                                                          \
      for (int q=0;q<16;q++) ov[q] = f2bf(st[q]);                                \
      uint4 u0,u1; pack16(ov,u0,u1);                                             \
      *(uint4*)&S[off + (IDX)*4096]     = u0;                                    \
      *(uint4*)&S[off + (IDX)*4096 + 8] = u1;                                    \
      float a = expf(cum[cb + (size_t)(c4*4 + (IDX))*64 + 63]);                  \
      const unsigned short* sp0 = (const unsigned short*)&PA;                    \
      const unsigned short* sp1 = (const unsigned short*)&PB;                    \
      _Pragma("unroll")                                                          \
      for (int q=0;q<8;q++) st[q]   = st[q]*a   + bf2f(sp0[q]);                  \
      _Pragma("unroll")                                                          \
      for (int q=0;q<8;q++) st[8+q] = st[8+q]*a + bf2f(sp1[q]);                  \
      if (c4 < 15){                                                              \
        PA = *(const uint4*)&S[off + ((IDX)+4)*4096];                            \
        PB = *(const uint4*)&S[off + ((IDX)+4)*4096 + 8];                        \
      }                                                                          \
    }
    PB_STEP(pa0,pb0,0)
    PB_STEP(pa1,pb1,1)
    PB_STEP(pa2,pb2,2)
    PB_STEP(pa3,pb3,3)
#undef PB_STEP
  }
}

// ---------------- K7: phase C — per-chunk outputs via MFMA ----------------
// writes y into zx's dead xBC columns: yout[(b*L+t)*ZLD + 1536 + h*64+p]
__global__ void phaseC_kernel(const unsigned short* __restrict__ Cn,
                              const unsigned short* __restrict__ Bn,
                              const unsigned short* __restrict__ xsT,
                              const unsigned short* __restrict__ hinit,
                              const float* __restrict__ cum, const float* __restrict__ dtT,
                              const float* __restrict__ D_skip,
                              unsigned short* __restrict__ yout)
{
  int h = blockIdx.x, chk = blockIdx.y, b = blockIdx.z;
  int tid = threadIdx.x, lane = tid&63, wv = tid>>6;
  __shared__ __align__(16) unsigned short Ct[64*72];
  __shared__ __align__(16) unsigned short Bt[64*72];
  __shared__ __align__(16) unsigned short Xt[64*72];
  __shared__ __align__(16) unsigned short Ht[64*72];
  __shared__ __align__(16) unsigned short Mt[64*72];
  __shared__ float cumL[64], dtL[64], aL[64];
  int l0 = chk*64;
  size_t cb = ((size_t)((b*DH+h)*64 + chk))*64;
  size_t tb = cb*64;
  {
    int r = tid>>2, c16 = (tid&3)*16;
    size_t lrow = (size_t)(b*DL + l0 + r);
    #pragma unroll
    for (int half=0; half<2; half++){
      int c8 = c16 + half*8;
      *(uint4*)&Ct[r*72 + c8] = *(const uint4*)&Cn[lrow*64 + c8];
      *(uint4*)&Bt[r*72 + c8] = *(const uint4*)&Bn[lrow*64 + c8];
      *(uint4*)&Xt[r*72 + c8] = *(const uint4*)&xsT[tb + r*64 + c8];
      *(uint4*)&Ht[r*72 + c8] = *(const uint4*)&hinit[tb + r*64 + c8];
    }
  }
  if (tid < 64){
    float cv = cum[cb + tid];
    cumL[tid] = cv; aL[tid] = expf(cv); dtL[tid] = dtT[cb + tid];
  }
  __syncthreads();
  int ml = lane&15, ko8 = (lane>>4)*8, r0 = (lane>>4)*4;
  int t0 = (wv&1)*32, q0 = (wv>>1)*32;   // q0 = s-quadrant for G, p-quadrant for Y
  f32x4 accG[2][2];
  #pragma unroll
  for (int i=0;i<2;i++)
    #pragma unroll
    for (int j=0;j<2;j++) accG[i][j] = (f32x4){0.f,0.f,0.f,0.f};
  #pragma unroll
  for (int kn=0; kn<64; kn+=32){
    bf16x8 a0 = *(const bf16x8*)&Ct[(t0+ml)*72    + kn + ko8];
    bf16x8 a1 = *(const bf16x8*)&Ct[(t0+16+ml)*72 + kn + ko8];
    bf16x8 b0 = *(const bf16x8*)&Bt[(q0+ml)*72    + kn + ko8];
    bf16x8 b1 = *(const bf16x8*)&Bt[(q0+16+ml)*72 + kn + ko8];
    accG[0][0] = __builtin_amdgcn_mfma_f32_16x16x32_bf16(a0,b0,accG[0][0],0,0,0);
    accG[0][1] = __builtin_amdgcn_mfma_f32_16x16x32_bf16(a0,b1,accG[0][1],0,0,0);
    accG[1][0] = __builtin_amdgcn_mfma_f32_16x16x32_bf16(a1,b0,accG[1][0],0,0,0);
    accG[1][1] = __builtin_amdgcn_mfma_f32_16x16x32_bf16(a1,b1,accG[1][1],0,0,0);
  }
  __syncthreads();
  // M[t][s] = (s<=t) ? G * exp(cum_t - cum_s) * dt_s : 0
  #pragma unroll
  for (int i=0;i<2;i++){
    #pragma unroll
    for (int j=0;j<2;j++){
      int s = q0 + j*16 + ml;
      int tbs = t0 + i*16 + r0;
      #pragma unroll
      for (int r=0;r<4;r++){
        int t = tbs + r;
        float m = 0.f;
        if (s <= t) m = accG[i][j][r] * expf(cumL[t]-cumL[s]) * dtL[s];
        Mt[t*72 + s] = f2bf(m);
      }
    }
  }
  // Ct <- a_t * Ct (in place, post-G)
  {
    int rr = tid>>2; int cc = (tid&3)*16;
    float at = aL[rr];
    #pragma unroll
    for (int q=0;q<16;q++){
      int idx = rr*72 + cc + q;
      Ct[idx] = f2bf(bf2f(Ct[idx]) * at);
    }
  }
  __syncthreads();
  f32x4 accY[2][2];
  #pragma unroll
  for (int i=0;i<2;i++)
    #pragma unroll
    for (int j=0;j<2;j++) accY[i][j] = (f32x4){0.f,0.f,0.f,0.f};
  #pragma unroll
  for (int ks=0; ks<64; ks+=32){
    bf16x8 a0 = *(const bf16x8*)&Mt[(t0+ml)*72    + ks + ko8];
    bf16x8 a1 = *(const bf16x8*)&Mt[(t0+16+ml)*72 + ks + ko8];
    bf16x8 b0 = *(const bf16x8*)&Xt[(q0+ml)*72    + ks + ko8];
    bf16x8 b1 = *(const bf16x8*)&Xt[(q0+16+ml)*72 + ks + ko8];
    accY[0][0] = __builtin_amdgcn_mfma_f32_16x16x32_bf16(a0,b0,accY[0][0],0,0,0);
    accY[0][1] = __builtin_amdgcn_mfma_f32_16x16x32_bf16(a0,b1,accY[0][1],0,0,0);
    accY[1][0] = __builtin_amdgcn_mfma_f32_16x16x32_bf16(a1,b0,accY[1][0],0,0,0);
    accY[1][1] = __builtin_amdgcn_mfma_f32_16x16x32_bf16(a1,b1,accY[1][1],0,0,0);
  }
  #pragma unroll
  for (int kn=0; kn<64; kn+=32){
    bf16x8 a0 = *(const bf16x8*)&Ct[(t0+ml)*72    + kn + ko8];
    bf16x8 a1 = *(const bf16x8*)&Ct[(t0+16+ml)*72 + kn + ko8];
    bf16x8 b0 = *(const bf16x8*)&Ht[(q0+ml)*72    + kn + ko8];
    bf16x8 b1 = *(const bf16x8*)&Ht[(q0+16+ml)*72 + kn + ko8];
    accY[0][0] = __builtin_amdgcn_mfma_f32_16x16x32_bf16(a0,b0,accY[0][0],0,0,0);
    accY[0][1] = __builtin_amdgcn_mfma_f32_16x16x32_bf16(a0,b1,accY[0][1],0,0,0);
    accY[1][0] = __builtin_amdgcn_mfma_f32_16x16x32_bf16(a1,b0,accY[1][0],0,0,0);
    accY[1][1] = __builtin_amdgcn_mfma_f32_16x16x32_bf16(a1,b1,accY[1][1],0,0,0);
  }
  float dsk = D_skip[h];
  #pragma unroll
  for (int i=0;i<2;i++){
    #pragma unroll
    for (int j=0;j<2;j++){
      int p = q0 + j*16 + ml;
      int tbs = t0 + i*16 + r0;
      #pragma unroll
      for (int r=0;r<4;r++){
        int t = tbs + r;
        float xv = bf2f(Xt[p*72 + t]);
        float v = accY[i][j][r] + dsk*xv;
        yout[(size_t)(b*DL + l0 + t)*ZLD + 1536 + h*64 + p] = f2bf(v);
      }
    }
  }
}

// ---------------- K8: gating + RMSNorm -> g (IN PLACE over z cols of zx) ----------------
__global__ void gate_kernel(unsigned short* __restrict__ zx,
                            const float* __restrict__ nw)
{
  int row = blockIdx.x; int tid = threadIdx.x;
  unsigned short* zr = zx + (size_t)row*ZLD;       // z cols [0,1536), y cols [1536,3072)
  float gv[6]; float s2 = 0.f;
  #pragma unroll
  for (int k=0;k<6;k++){
    int i = tid + k*256;
    float yv = bf2f(zr[1536 + i]);
    float zv = bf2f(zr[i]);
    float t = yv * siluf(zv);
    gv[k] = t; s2 += t*t;
  }
  for (int off=32; off>0; off>>=1) s2 += __shfl_down(s2, off);
  __shared__ float red[5];
  int wv = tid>>6;
  if ((tid&63)==0) red[wv] = s2;
  __syncthreads();
  if (tid==0) red[4] = red[0]+red[1]+red[2]+red[3];
  __syncthreads();
  float scale = rsqrtf(red[4]*(1.f/1536.f) + 1e-5f);
  #pragma unroll
  for (int k=0;k<6;k++){
    int i = tid + k*256;
    zr[i] = f2bf(gv[k]*scale*nw[i]);   // g overwrites z in place (each thread wrote only what it read)
  }
}

// ---------------- launch ----------------
extern "C" void kernel_launch(void* const* d_in, const int* in_sizes, int n_in,
                              void* d_out, int out_size, void* d_ws, size_t ws_size,
                              hipStream_t stream)
{
  (void)in_sizes; (void)n_in; (void)out_size; (void)ws_size;
  const float* x      = (const float*)d_in[0];
  const float* ln_w   = (const float*)d_in[1];
  const float* ln_b   = (const float*)d_in[2];
  const float* Win    = (const float*)d_in[3];
  const float* conv_w = (const float*)d_in[4];
  const float* conv_b = (const float*)d_in[5];
  const float* dt_bias= (const float*)d_in[6];
  const float* A_log  = (const float*)d_in[7];
  const float* D_skip = (const float*)d_in[8];
  const float* norm_w = (const float*)d_in[9];
  const float* Wout   = (const float*)d_in[10];
  float* out = (float*)d_out;
  char* ws = (char*)d_ws;

  // ws layout (total ~340 MB). S/hinit (100.66 MB) lives in d_out (dead until GEMM2).
  unsigned short* zx    = (unsigned short*)(ws + 0);            // 209,715,200  (z | xBC; y overlays xBC; g overlays z)
  unsigned short* xsT   = (unsigned short*)(ws + 209715200);    // 100,663,296  (xn overlaid: disjoint lifetime)
  unsigned short* xn    = xsT;                                  //  50,331,648  (dead after GEMM1, before conv writes xsT)
  unsigned short* winb  = (unsigned short*)(ws + 310378496);    //   4,952,064
  unsigned short* woutb = (unsigned short*)(ws + 315330560);    //   2,359,296
  float*          dtb   = (float*)        (ws + 317689856);     //   3,145,728
  float*          dtT   = (float*)        (ws + 320835584);     //   3,145,728
  float*          cum   = (float*)        (ws + 323981312);     //   3,145,728
  unsigned short* Bn    = (unsigned short*)(ws + 327127040);    //   4,194,304
  unsigned short* Cn    = (unsigned short*)(ws + 331321344);    //   4,194,304
  unsigned short* BT    = (unsigned short*)(ws + 335515648);    //   4,194,304  (end 339,709,952)
  unsigned short* S     = (unsigned short*)d_out;               // 100,663,296 == out_size*4 exactly

  cvt_kernel  <<<3570, 256, 0, stream>>>(Win, Wout, winb, woutb);
  ln_kernel   <<<BL, 256, 0, stream>>>(x, ln_w, ln_b, xn);
  gemm_kernel<1><<<128*26, 256, 0, stream>>>(xn, winb, 768, 768, DIPD, 26, zx, dtb, dt_bias, nullptr, nullptr);
  conv_kernel <<<dim3(26,64,8), 256, 0, stream>>>(zx, conv_w, conv_b, xsT, Bn, Cn, BT);
  cum_kernel  <<<3072, 256, 0, stream>>>(dtb, A_log, cum, dtT);
  phaseA_kernel<<<dim3(64,24,8), 256, 0, stream>>>(xsT, BT, cum, dtT, S);
  phaseB_kernel<<<192, 256, 0, stream>>>(S, cum);
  phaseC_kernel<<<dim3(24,64,8), 256, 0, stream>>>(Cn, Bn, xsT, S, cum, dtT, D_skip, zx);
  gate_kernel <<<BL, 256, 0, stream>>>(zx, norm_w);
  gemm_kernel<2><<<128*6, 256, 0, stream>>>(zx, woutb, 1536, ZLD, DD, 6, nullptr, nullptr, nullptr, x, out);
}

// Round 5
// 861.068 us; speedup vs baseline: 1.1529x; 1.1529x over previous
//
#include <hip/hip_runtime.h>
#include <cstdint>

// Problem dims
#define DB   8
#define DL   4096
#define DD   768
#define DDI  1536
#define DN   64
#define DH   24
#define DP   64
#define DCD  1664
#define DIPD 3224
#define BL   (DB*DL)      // 32768 tokens
#define NCH  64           // chunks (L/64)
#define ZLD  3200         // zx row stride (z 1536 | xBC 1664)

typedef __attribute__((ext_vector_type(8))) short bf16x8;
typedef __attribute__((ext_vector_type(4))) float f32x4;

__device__ __forceinline__ unsigned short f2bf(float f){
  unsigned u = __float_as_uint(f);
  u += 0x7FFFu + ((u >> 16) & 1u);
  return (unsigned short)(u >> 16);
}
__device__ __forceinline__ float bf2f(unsigned short s){
  return __uint_as_float(((unsigned)s) << 16);
}
__device__ __forceinline__ unsigned pack2(unsigned short a, unsigned short b){
  return (unsigned)a | ((unsigned)b << 16);
}
__device__ __forceinline__ void pack16(const unsigned short* ov, uint4& u0, uint4& u1){
  u0.x = pack2(ov[0],ov[1]);  u0.y = pack2(ov[2],ov[3]);
  u0.z = pack2(ov[4],ov[5]);  u0.w = pack2(ov[6],ov[7]);
  u1.x = pack2(ov[8],ov[9]);  u1.y = pack2(ov[10],ov[11]);
  u1.z = pack2(ov[12],ov[13]); u1.w = pack2(ov[14],ov[15]);
}
__device__ __forceinline__ void async16(void* lds, const void* g){
  __builtin_amdgcn_global_load_lds((const __attribute__((address_space(1))) unsigned*)g,
                                   (__attribute__((address_space(3))) unsigned*)lds, 16, 0, 0);
}
__device__ __forceinline__ float softplusf(float v){
  return v > 15.f ? v : log1pf(expf(v));
}
__device__ __forceinline__ float siluf(float v){
  return v / (1.f + expf(-v));
}

// ---------------- K0: fp32 -> bf16 weight conversion (Win, Wout) ----------------
__global__ void cvt_kernel(const float* __restrict__ win, const float* __restrict__ wout,
                           unsigned short* __restrict__ winb, unsigned short* __restrict__ woutb){
  int i = blockIdx.x*256 + threadIdx.x;
  const int WN = (DIPD*DD)/4;   // 619008
  const int ON = (DD*DDI)/4;    // 294912
  if (i < WN){
    float4 v = ((const float4*)win)[i];
    uint2 o; o.x = pack2(f2bf(v.x), f2bf(v.y)); o.y = pack2(f2bf(v.z), f2bf(v.w));
    ((uint2*)winb)[i] = o;
  } else if (i < WN+ON){
    int j = i - WN;
    float4 v = ((const float4*)wout)[j];
    uint2 o; o.x = pack2(f2bf(v.x), f2bf(v.y)); o.y = pack2(f2bf(v.z), f2bf(v.w));
    ((uint2*)woutb)[j] = o;
  }
}

// ---------------- K1: LayerNorm -> xn (bf16) ----------------
__global__ void ln_kernel(const float* __restrict__ x, const float* __restrict__ w,
                          const float* __restrict__ bb, unsigned short* __restrict__ xn){
  int row = blockIdx.x; int tid = threadIdx.x;
  const float* xr = x + (size_t)row*DD;
  float v0=xr[tid], v1=xr[tid+256], v2=xr[tid+512];
  float s = v0+v1+v2;
  float s2 = v0*v0+v1*v1+v2*v2;
  for (int off=32; off>0; off>>=1){ s += __shfl_down(s, off); s2 += __shfl_down(s2, off); }
  __shared__ float red[10];
  int wv = tid>>6;
  if ((tid&63)==0){ red[wv]=s; red[4+wv]=s2; }
  __syncthreads();
  if (tid==0){
    float a=red[0]+red[1]+red[2]+red[3];
    float c=red[4]+red[5]+red[6]+red[7];
    red[8]=a*(1.f/768.f); red[9]=c*(1.f/768.f);
  }
  __syncthreads();
  float mu = red[8];
  float inv = rsqrtf(red[9]-mu*mu + 1e-5f);
  unsigned short* o = xn + (size_t)row*DD;
  o[tid]     = f2bf((v0-mu)*inv*w[tid]     + bb[tid]);
  o[tid+256] = f2bf((v1-mu)*inv*w[tid+256] + bb[tid+256]);
  o[tid+512] = f2bf((v2-mu)*inv*w[tid+512] + bb[tid+512]);
}

// ---------------- K2: bf16 MFMA GEMM (128x128, BK=32) — T3 minimal 2-phase pipeline ----------------
// Round-5 delta vs round-3 best (865us): double-buffered LDS + single barrier per K-iter.
//  - STAGE for tile t+1 is issued into the OTHER buffer BEFORE the ds_read+MFMA of tile t,
//    so the global_load_lds queue has a full iteration (~600cy of compute) to land instead
//    of being drained immediately (the m233 ~72% 2-phase stall). One __syncthreads per iter
//    (emits vmcnt(0)+lgkmcnt(0)+barrier) both publishes the staged buffer and protects the
//    just-read buffer from next iter's overwrite. [T3 recipe, m230/m248: +10-12% refcheck'd]
//  - LDS 32KB (2x16KB), regs 56V+64A=120 <= 128 -> 4 blocks/CU (vs 3.25), more TLP.
// MODE 1: zxbcdt = xn @ Win^T; cols [0,3200)->zx bf16 (stride ZLD), cols [3200,3224)->softplus(+dt_bias)->dt f32
// MODE 2: out = A(lda) @ Wout^T + x (fp32 store, nontemporal)
template<int MODE>
__launch_bounds__(256,4)
__global__ void gemm_kernel(const unsigned short* __restrict__ A,
                            const unsigned short* __restrict__ Bw,
                            int K, int lda, int Brows, int nbn,
                            unsigned short* __restrict__ zx, float* __restrict__ dtbuf,
                            const float* __restrict__ dt_bias,
                            const float* __restrict__ xres, float* __restrict__ outp)
{
  __shared__ __align__(16) unsigned short As[2*128*32];   // 16 KiB x2
  __shared__ __align__(16) unsigned short Bs[2*128*32];
  int tid = threadIdx.x; int lane = tid&63; int wv = tid>>6;
  // --- XCD-aware remap (nwg % 8 == 0 for both call sites), bn-fast for A-panel L2 reuse ---
  int nwg  = gridDim.x;
  int orig = blockIdx.x;
  int q    = nwg >> 3;
  int wgid = (orig & 7)*q + (orig >> 3);
  int bm = wgid / nbn, bn = wgid % nbn;

  const unsigned short* ap0 = A + (size_t)(bm*128 + wv*32 + (lane>>2))*lda + (lane&3)*8;
  const unsigned short* ap1 = ap0 + (size_t)16*lda;
  int rb0 = bn*128 + wv*32 + (lane>>2);      if (rb0 > Brows-1) rb0 = Brows-1;
  int rb1 = bn*128 + wv*32 + 16 + (lane>>2); if (rb1 > Brows-1) rb1 = Brows-1;
  const unsigned short* bp0 = Bw + (size_t)rb0*K + (lane&3)*8;
  const unsigned short* bp1 = Bw + (size_t)rb1*K + (lane&3)*8;
  unsigned short* la0 = &As[(wv*2)*512]; unsigned short* la1 = la0 + 512;
  unsigned short* lb0 = &Bs[(wv*2)*512]; unsigned short* lb1 = lb0 + 512;
  f32x4 acc[4][4];
  #pragma unroll
  for (int i=0;i<4;i++)
    #pragma unroll
    for (int j=0;j<4;j++) acc[i][j] = (f32x4){0.f,0.f,0.f,0.f};
  int mb = (wv&1)*64 + (lane&15);
  int nb = (wv>>1)*64 + (lane&15);
  int ko = (lane>>4)*8;

  // prologue: stage tile 0 into buffer 0, publish
  async16(la0, ap0); async16(la1, ap1);
  async16(lb0, bp0); async16(lb1, bp1);
  ap0 += 32; ap1 += 32; bp0 += 32; bp1 += 32;
  __syncthreads();

  int cur = 0;
  for (int k0=0; k0<K; k0+=32){
    // issue next tile's stage into the OTHER buffer (overlaps this iter's compute)
    if (k0 + 32 < K){
      int nxt = (cur^1)*4096;
      async16(la0 + nxt, ap0); async16(la1 + nxt, ap1);
      async16(lb0 + nxt, bp0); async16(lb1 + nxt, bp1);
      ap0 += 32; ap1 += 32; bp0 += 32; bp1 += 32;
    }
    const unsigned short* Ab = &As[cur*4096];
    const unsigned short* Bb = &Bs[cur*4096];
    bf16x8 af[4], bfr[4];
    #pragma unroll
    for (int i=0;i<4;i++) af[i]  = *(const bf16x8*)&Ab[(mb+i*16)*32 + ko];
    #pragma unroll
    for (int j=0;j<4;j++) bfr[j] = *(const bf16x8*)&Bb[(nb+j*16)*32 + ko];
    #pragma unroll
    for (int i=0;i<4;i++)
      #pragma unroll
      for (int j=0;j<4;j++)
        acc[i][j] = __builtin_amdgcn_mfma_f32_16x16x32_bf16(af[i], bfr[j], acc[i][j], 0, 0, 0);
    // single barrier per iter: drains vmcnt (next buffer staged) and guarantees all waves
    // finished reading buf[cur] (their ds_reads completed before their MFMAs issued).
    __syncthreads();
    cur ^= 1;
  }

  int mrow0 = bm*128 + (wv&1)*64 + (lane>>4)*4;
  int ncol0 = bn*128 + (wv>>1)*64 + (lane&15);
  #pragma unroll
  for (int i=0;i<4;i++){
    #pragma unroll
    for (int j=0;j<4;j++){
      int col = ncol0 + j*16;
      #pragma unroll
      for (int r=0;r<4;r++){
        int row = mrow0 + i*16 + r;
        float v = acc[i][j][r];
        if (MODE == 1){
          if (bn < 25){
            zx[(size_t)row*ZLD + col] = f2bf(v);
          } else {
            int cc = col - 3200;
            if (cc >= 0 && cc < DH) dtbuf[(size_t)row*DH + cc] = softplusf(v + dt_bias[cc]);
          }
        } else {
          float xr = __builtin_nontemporal_load(&xres[(size_t)row*DD + col]);
          __builtin_nontemporal_store(v + xr, &outp[(size_t)row*DD + col]);
        }
      }
    }
  }
}

// ---------------- K3: depthwise causal conv K=4 + bias + silu ----------------
// bx<24 -> xsT[b][h=bx][chunk][p][t]; bx==24 -> Bn (b,l,n) + BT (b,chunk,n,t); bx==25 -> Cn (b,l,n)
__global__ void conv_kernel(const unsigned short* __restrict__ zx,
                            const float* __restrict__ cw, const float* __restrict__ cb,
                            unsigned short* __restrict__ xsT, unsigned short* __restrict__ Bn,
                            unsigned short* __restrict__ Cn, unsigned short* __restrict__ BT)
{
  int bx = blockIdx.x, by = blockIdx.y, b = blockIdx.z;
  int tid = threadIdx.x;
  __shared__ __align__(16) unsigned short in_s[67*64];
  int l0 = by*64;
  for (int idx = tid; idx < 67*8; idx += 256){
    int r = idx >> 3, c8 = idx & 7;
    int l = l0 - 3 + r;
    uint4 v = make_uint4(0u,0u,0u,0u);
    if (l >= 0) v = *(const uint4*)&zx[(size_t)(b*DL + l)*ZLD + 1536 + bx*64 + c8*8];
    *(uint4*)&in_s[r*64 + c8*8] = v;
  }
  __syncthreads();
  int c = tid & 63, li = tid >> 6;
  int chn = bx*64 + c;
  float w0=cw[chn*4+0], w1=cw[chn*4+1], w2=cw[chn*4+2], w3=cw[chn*4+3];
  float bias = cb[chn];
  unsigned short ov[16];
  #pragma unroll
  for (int q=0;q<16;q++){
    int t = li*16 + q;
    float a = bias
      + w0*bf2f(in_s[(t+0)*64 + c])
      + w1*bf2f(in_s[(t+1)*64 + c])
      + w2*bf2f(in_s[(t+2)*64 + c])
      + w3*bf2f(in_s[(t+3)*64 + c]);
    ov[q] = f2bf(siluf(a));
  }
  if (bx < 24){
    size_t base = ((((size_t)(b*DH + bx))*64 + by)*64 + c)*64 + li*16;
    uint4 u0,u1; pack16(ov,u0,u1);
    *(uint4*)&xsT[base]   = u0;
    *(uint4*)&xsT[base+8] = u1;
  } else if (bx == 24){
    #pragma unroll
    for (int q=0;q<16;q++)
      Bn[(size_t)(b*DL + l0 + li*16 + q)*64 + c] = ov[q];
    size_t bt = (((size_t)(b*64 + by))*64 + c)*64 + li*16;
    uint4 u0,u1; pack16(ov,u0,u1);
    *(uint4*)&BT[bt]   = u0;
    *(uint4*)&BT[bt+8] = u1;
  } else {
    #pragma unroll
    for (int q=0;q<16;q++)
      Cn[(size_t)(b*DL + l0 + li*16 + q)*64 + c] = ov[q];
  }
}

// ---------------- K4: per-(b,h,chunk) logdA cumsum (fp32) ----------------
__global__ void cum_kernel(const float* __restrict__ dt, const float* __restrict__ A_log,
                           float* __restrict__ cum, float* __restrict__ dtT)
{
  int tid = threadIdx.x; int lane = tid&63; int wv = tid>>6;
  int idx = blockIdx.x*4 + wv;            // (b*24+h)*64 + ch
  int b = idx / 1536; int r = idx % 1536; int h = r >> 6; int chk = r & 63;
  float dv = dt[((size_t)(b*DL + chk*64 + lane))*DH + h];
  float ld = -dv * expf(A_log[h]);
  for (int off=1; off<64; off<<=1){
    float v = __shfl_up(ld, off);
    if (lane >= off) ld += v;
  }
  size_t cb = (size_t)idx*64;
  cum[cb + lane] = ld;
  dtT[cb + lane] = dv;
}

// ---------------- K5: phase A — per-chunk state contribution S = Xw^T @ B ----------------
__global__ void phaseA_kernel(const unsigned short* __restrict__ xsT,
                              const unsigned short* __restrict__ BT,
                              const float* __restrict__ cum, const float* __restrict__ dtT,
                              unsigned short* __restrict__ S)
{
  int chk = blockIdx.x, h = blockIdx.y, b = blockIdx.z;
  int tid = threadIdx.x, lane = tid&63, wv = tid>>6;
  __shared__ __align__(16) unsigned short Xw[64*72];
  __shared__ __align__(16) unsigned short Bl[64*72];
  __shared__ float wl[64];
  size_t cbase = ((size_t)((b*DH + h)*64 + chk))*64;
  if (tid < 64){
    float cv  = cum[cbase + tid];
    float c63 = cum[cbase + 63];
    wl[tid] = expf(c63 - cv) * dtT[cbase + tid];
  }
  __syncthreads();
  size_t xbase = cbase*64;
  size_t btb = ((size_t)(b*64 + chk))*4096;
  {
    int p = tid>>2, t16 = (tid&3)*16;
    #pragma unroll
    for (int half=0; half<2; half++){
      int t8 = t16 + half*8;
      uint4 xv = *(const uint4*)&xsT[xbase + p*64 + t8];
      const unsigned short* xp = (const unsigned short*)&xv;
      unsigned short ow[8];
      #pragma unroll
      for (int j=0;j<8;j++) ow[j] = f2bf(bf2f(xp[j]) * wl[t8+j]);
      uint4 u0; u0.x=pack2(ow[0],ow[1]); u0.y=pack2(ow[2],ow[3]); u0.z=pack2(ow[4],ow[5]); u0.w=pack2(ow[6],ow[7]);
      *(uint4*)&Xw[p*72 + t8] = u0;
      *(uint4*)&Bl[p*72 + t8] = *(const uint4*)&BT[btb + p*64 + t8];
    }
  }
  __syncthreads();
  int p0 = (wv&1)*32, n0 = (wv>>1)*32;
  int ml = lane&15, ko = (lane>>4)*8;
  f32x4 acc[2][2];
  #pragma unroll
  for (int i=0;i<2;i++)
    #pragma unroll
    for (int j=0;j<2;j++) acc[i][j] = (f32x4){0.f,0.f,0.f,0.f};
  #pragma unroll
  for (int ks=0; ks<64; ks+=32){
    bf16x8 a0 = *(const bf16x8*)&Xw[(p0+ml)*72    + ks + ko];
    bf16x8 a1 = *(const bf16x8*)&Xw[(p0+16+ml)*72 + ks + ko];
    bf16x8 b0 = *(const bf16x8*)&Bl[(n0+ml)*72    + ks + ko];
    bf16x8 b1 = *(const bf16x8*)&Bl[(n0+16+ml)*72 + ks + ko];
    acc[0][0] = __builtin_amdgcn_mfma_f32_16x16x32_bf16(a0,b0,acc[0][0],0,0,0);
    acc[0][1] = __builtin_amdgcn_mfma_f32_16x16x32_bf16(a0,b1,acc[0][1],0,0,0);
    acc[1][0] = __builtin_amdgcn_mfma_f32_16x16x32_bf16(a1,b0,acc[1][0],0,0,0);
    acc[1][1] = __builtin_amdgcn_mfma_f32_16x16x32_bf16(a1,b1,acc[1][1],0,0,0);
  }
  #pragma unroll
  for (int i=0;i<2;i++){
    #pragma unroll
    for (int j=0;j<2;j++){
      int n = n0 + j*16 + ml;
      int pr = p0 + i*16 + (lane>>4)*4;
      #pragma unroll
      for (int r=0;r<4;r++)
        S[xbase + (size_t)(pr+r)*64 + n] = f2bf(acc[i][j][r]);
    }
  }
}

// ---------------- K6: phase B — sequential cross-chunk state recurrence (IN PLACE: hinit==S) ----------------
__global__ void phaseB_kernel(unsigned short* __restrict__ S,   // becomes hinit
                              const float* __restrict__ cum)
{
  int bh = blockIdx.x; int tid = threadIdx.x;
  size_t base = (size_t)bh * (64*4096) + (size_t)tid*16;
  size_t cb = (size_t)bh * 4096;
  float st[16];
  #pragma unroll
  for (int q=0;q<16;q++) st[q] = 0.f;
  uint4 pa0 = *(const uint4*)&S[base];            uint4 pb0 = *(const uint4*)&S[base + 8];
  uint4 pa1 = *(const uint4*)&S[base + 4096];     uint4 pb1 = *(const uint4*)&S[base + 4096 + 8];
  uint4 pa2 = *(const uint4*)&S[base + 2*4096];   uint4 pb2 = *(const uint4*)&S[base + 2*4096 + 8];
  uint4 pa3 = *(const uint4*)&S[base + 3*4096];   uint4 pb3 = *(const uint4*)&S[base + 3*4096 + 8];
  for (int c4 = 0; c4 < 16; ++c4){
    size_t off = base + (size_t)c4*(4*4096);
#define PB_STEP(PA,PB,IDX)                                                       \
    {                                                                            \
      unsigned short ov[16];                                                     \
      _Pragma("unroll")                                                          \
      for (int q=0;q<16;q++) ov[q] = f2bf(st[q]);                                \
      uint4 u0,u1; pack16(ov,u0,u1);                                             \
      *(uint4*)&S[off + (IDX)*4096]     = u0;                                    \
      *(uint4*)&S[off + (IDX)*4096 + 8] = u1;                                    \
      float a = expf(cum[cb + (size_t)(c4*4 + (IDX))*64 + 63]);                  \
      const unsigned short* sp0 = (const unsigned short*)&PA;                    \
      const unsigned short* sp1 = (const unsigned short*)&PB;                    \
      _Pragma("unroll")                                                          \
      for (int q=0;q<8;q++) st[q]   = st[q]*a   + bf2f(sp0[q]);                  \
      _Pragma("unroll")                                                          \
      for (int q=0;q<8;q++) st[8+q] = st[8+q]*a + bf2f(sp1[q]);                  \
      if (c4 < 15){                                                              \
        PA = *(const uint4*)&S[off + ((IDX)+4)*4096];                            \
        PB = *(const uint4*)&S[off + ((IDX)+4)*4096 + 8];                        \
      }                                                                          \
    }
    PB_STEP(pa0,pb0,0)
    PB_STEP(pa1,pb1,1)
    PB_STEP(pa2,pb2,2)
    PB_STEP(pa3,pb3,3)
#undef PB_STEP
  }
}

// ---------------- K7: phase C — per-chunk outputs via MFMA ----------------
// writes y into zx's dead xBC columns: yout[(b*L+t)*ZLD + 1536 + h*64+p]
__global__ void phaseC_kernel(const unsigned short* __restrict__ Cn,
                              const unsigned short* __restrict__ Bn,
                              const unsigned short* __restrict__ xsT,
                              const unsigned short* __restrict__ hinit,
                              const float* __restrict__ cum, const float* __restrict__ dtT,
                              const float* __restrict__ D_skip,
                              unsigned short* __restrict__ yout)
{
  int h = blockIdx.x, chk = blockIdx.y, b = blockIdx.z;
  int tid = threadIdx.x, lane = tid&63, wv = tid>>6;
  __shared__ __align__(16) unsigned short Ct[64*72];
  __shared__ __align__(16) unsigned short Bt[64*72];
  __shared__ __align__(16) unsigned short Xt[64*72];
  __shared__ __align__(16) unsigned short Ht[64*72];
  __shared__ __align__(16) unsigned short Mt[64*72];
  __shared__ float cumL[64], dtL[64], aL[64];
  int l0 = chk*64;
  size_t cb = ((size_t)((b*DH+h)*64 + chk))*64;
  size_t tb = cb*64;
  {
    int r = tid>>2, c16 = (tid&3)*16;
    size_t lrow = (size_t)(b*DL + l0 + r);
    #pragma unroll
    for (int half=0; half<2; half++){
      int c8 = c16 + half*8;
      *(uint4*)&Ct[r*72 + c8] = *(const uint4*)&Cn[lrow*64 + c8];
      *(uint4*)&Bt[r*72 + c8] = *(const uint4*)&Bn[lrow*64 + c8];
      *(uint4*)&Xt[r*72 + c8] = *(const uint4*)&xsT[tb + r*64 + c8];
      *(uint4*)&Ht[r*72 + c8] = *(const uint4*)&hinit[tb + r*64 + c8];
    }
  }
  if (tid < 64){
    float cv = cum[cb + tid];
    cumL[tid] = cv; aL[tid] = expf(cv); dtL[tid] = dtT[cb + tid];
  }
  __syncthreads();
  int ml = lane&15, ko8 = (lane>>4)*8, r0 = (lane>>4)*4;
  int t0 = (wv&1)*32, q0 = (wv>>1)*32;   // q0 = s-quadrant for G, p-quadrant for Y
  f32x4 accG[2][2];
  #pragma unroll
  for (int i=0;i<2;i++)
    #pragma unroll
    for (int j=0;j<2;j++) accG[i][j] = (f32x4){0.f,0.f,0.f,0.f};
  #pragma unroll
  for (int kn=0; kn<64; kn+=32){
    bf16x8 a0 = *(const bf16x8*)&Ct[(t0+ml)*72    + kn + ko8];
    bf16x8 a1 = *(const bf16x8*)&Ct[(t0+16+ml)*72 + kn + ko8];
    bf16x8 b0 = *(const bf16x8*)&Bt[(q0+ml)*72    + kn + ko8];
    bf16x8 b1 = *(const bf16x8*)&Bt[(q0+16+ml)*72 + kn + ko8];
    accG[0][0] = __builtin_amdgcn_mfma_f32_16x16x32_bf16(a0,b0,accG[0][0],0,0,0);
    accG[0][1] = __builtin_amdgcn_mfma_f32_16x16x32_bf16(a0,b1,accG[0][1],0,0,0);
    accG[1][0] = __builtin_amdgcn_mfma_f32_16x16x32_bf16(a1,b0,accG[1][0],0,0,0);
    accG[1][1] = __builtin_amdgcn_mfma_f32_16x16x32_bf16(a1,b1,accG[1][1],0,0,0);
  }
  __syncthreads();
  // M[t][s] = (s<=t) ? G * exp(cum_t - cum_s) * dt_s : 0
  #pragma unroll
  for (int i=0;i<2;i++){
    #pragma unroll
    for (int j=0;j<2;j++){
      int s = q0 + j*16 + ml;
      int tbs = t0 + i*16 + r0;
      #pragma unroll
      for (int r=0;r<4;r++){
        int t = tbs + r;
        float m = 0.f;
        if (s <= t) m = accG[i][j][r] * expf(cumL[t]-cumL[s]) * dtL[s];
        Mt[t*72 + s] = f2bf(m);
      }
    }
  }
  // Ct <- a_t * Ct (in place, post-G)
  {
    int rr = tid>>2; int cc = (tid&3)*16;
    float at = aL[rr];
    #pragma unroll
    for (int q=0;q<16;q++){
      int idx = rr*72 + cc + q;
      Ct[idx] = f2bf(bf2f(Ct[idx]) * at);
    }
  }
  __syncthreads();
  f32x4 accY[2][2];
  #pragma unroll
  for (int i=0;i<2;i++)
    #pragma unroll
    for (int j=0;j<2;j++) accY[i][j] = (f32x4){0.f,0.f,0.f,0.f};
  #pragma unroll
  for (int ks=0; ks<64; ks+=32){
    bf16x8 a0 = *(const bf16x8*)&Mt[(t0+ml)*72    + ks + ko8];
    bf16x8 a1 = *(const bf16x8*)&Mt[(t0+16+ml)*72 + ks + ko8];
    bf16x8 b0 = *(const bf16x8*)&Xt[(q0+ml)*72    + ks + ko8];
    bf16x8 b1 = *(const bf16x8*)&Xt[(q0+16+ml)*72 + ks + ko8];
    accY[0][0] = __builtin_amdgcn_mfma_f32_16x16x32_bf16(a0,b0,accY[0][0],0,0,0);
    accY[0][1] = __builtin_amdgcn_mfma_f32_16x16x32_bf16(a0,b1,accY[0][1],0,0,0);
    accY[1][0] = __builtin_amdgcn_mfma_f32_16x16x32_bf16(a1,b0,accY[1][0],0,0,0);
    accY[1][1] = __builtin_amdgcn_mfma_f32_16x16x32_bf16(a1,b1,accY[1][1],0,0,0);
  }
  #pragma unroll
  for (int kn=0; kn<64; kn+=32){
    bf16x8 a0 = *(const bf16x8*)&Ct[(t0+ml)*72    + kn + ko8];
    bf16x8 a1 = *(const bf16x8*)&Ct[(t0+16+ml)*72 + kn + ko8];
    bf16x8 b0 = *(const bf16x8*)&Ht[(q0+ml)*72    + kn + ko8];
    bf16x8 b1 = *(const bf16x8*)&Ht[(q0+16+ml)*72 + kn + ko8];
    accY[0][0] = __builtin_amdgcn_mfma_f32_16x16x32_bf16(a0,b0,accY[0][0],0,0,0);
    accY[0][1] = __builtin_amdgcn_mfma_f32_16x16x32_bf16(a0,b1,accY[0][1],0,0,0);
    accY[1][0] = __builtin_amdgcn_mfma_f32_16x16x32_bf16(a1,b0,accY[1][0],0,0,0);
    accY[1][1] = __builtin_amdgcn_mfma_f32_16x16x32_bf16(a1,b1,accY[1][1],0,0,0);
  }
  float dsk = D_skip[h];
  #pragma unroll
  for (int i=0;i<2;i++){
    #pragma unroll
    for (int j=0;j<2;j++){
      int p = q0 + j*16 + ml;
      int tbs = t0 + i*16 + r0;
      #pragma unroll
      for (int r=0;r<4;r++){
        int t = tbs + r;
        float xv = bf2f(Xt[p*72 + t]);
        float v = accY[i][j][r] + dsk*xv;
        yout[(size_t)(b*DL + l0 + t)*ZLD + 1536 + h*64 + p] = f2bf(v);
      }
    }
  }
}

// ---------------- K8: gating + RMSNorm -> g (IN PLACE over z cols of zx) ----------------
__global__ void gate_kernel(unsigned short* __restrict__ zx,
                            const float* __restrict__ nw)
{
  int row = blockIdx.x; int tid = threadIdx.x;
  unsigned short* zr = zx + (size_t)row*ZLD;       // z cols [0,1536), y cols [1536,3072)
  float gv[6]; float s2 = 0.f;
  #pragma unroll
  for (int k=0;k<6;k++){
    int i = tid + k*256;
    float yv = bf2f(zr[1536 + i]);
    float zv = bf2f(zr[i]);
    float t = yv * siluf(zv);
    gv[k] = t; s2 += t*t;
  }
  for (int off=32; off>0; off>>=1) s2 += __shfl_down(s2, off);
  __shared__ float red[5];
  int wv = tid>>6;
  if ((tid&63)==0) red[wv] = s2;
  __syncthreads();
  if (tid==0) red[4] = red[0]+red[1]+red[2]+red[3];
  __syncthreads();
  float scale = rsqrtf(red[4]*(1.f/1536.f) + 1e-5f);
  #pragma unroll
  for (int k=0;k<6;k++){
    int i = tid + k*256;
    zr[i] = f2bf(gv[k]*scale*nw[i]);   // g overwrites z in place (each thread wrote only what it read)
  }
}

// ---------------- launch ----------------
extern "C" void kernel_launch(void* const* d_in, const int* in_sizes, int n_in,
                              void* d_out, int out_size, void* d_ws, size_t ws_size,
                              hipStream_t stream)
{
  (void)in_sizes; (void)n_in; (void)out_size; (void)ws_size;
  const float* x      = (const float*)d_in[0];
  const float* ln_w   = (const float*)d_in[1];
  const float* ln_b   = (const float*)d_in[2];
  const float* Win    = (const float*)d_in[3];
  const float* conv_w = (const float*)d_in[4];
  const float* conv_b = (const float*)d_in[5];
  const float* dt_bias= (const float*)d_in[6];
  const float* A_log  = (const float*)d_in[7];
  const float* D_skip = (const float*)d_in[8];
  const float* norm_w = (const float*)d_in[9];
  const float* Wout   = (const float*)d_in[10];
  float* out = (float*)d_out;
  char* ws = (char*)d_ws;

  // ws layout (total ~340 MB). S/hinit (100.66 MB) lives in d_out (dead until GEMM2).
  unsigned short* zx    = (unsigned short*)(ws + 0);            // 209,715,200  (z | xBC; y overlays xBC; g overlays z)
  unsigned short* xsT   = (unsigned short*)(ws + 209715200);    // 100,663,296  (xn overlaid: disjoint lifetime)
  unsigned short* xn    = xsT;                                  //  50,331,648  (dead after GEMM1, before conv writes xsT)
  unsigned short* winb  = (unsigned short*)(ws + 310378496);    //   4,952,064
  unsigned short* woutb = (unsigned short*)(ws + 315330560);    //   2,359,296
  float*          dtb   = (float*)        (ws + 317689856);     //   3,145,728
  float*          dtT   = (float*)        (ws + 320835584);     //   3,145,728
  float*          cum   = (float*)        (ws + 323981312);     //   3,145,728
  unsigned short* Bn    = (unsigned short*)(ws + 327127040);    //   4,194,304
  unsigned short* Cn    = (unsigned short*)(ws + 331321344);    //   4,194,304
  unsigned short* BT    = (unsigned short*)(ws + 335515648);    //   4,194,304  (end 339,709,952)
  unsigned short* S     = (unsigned short*)d_out;               // 100,663,296 == out_size*4 exactly

  cvt_kernel  <<<3570, 256, 0, stream>>>(Win, Wout, winb, woutb);
  ln_kernel   <<<BL, 256, 0, stream>>>(x, ln_w, ln_b, xn);
  gemm_kernel<1><<<256*26, 256, 0, stream>>>(xn, winb, 768, 768, DIPD, 26, zx, dtb, dt_bias, nullptr, nullptr);
  conv_kernel <<<dim3(26,64,8), 256, 0, stream>>>(zx, conv_w, conv_b, xsT, Bn, Cn, BT);
  cum_kernel  <<<3072, 256, 0, stream>>>(dtb, A_log, cum, dtT);
  phaseA_kernel<<<dim3(64,24,8), 256, 0, stream>>>(xsT, BT, cum, dtT, S);
  phaseB_kernel<<<192, 256, 0, stream>>>(S, cum);
  phaseC_kernel<<<dim3(24,64,8), 256, 0, stream>>>(Cn, Bn, xsT, S, cum, dtT, D_skip, zx);
  gate_kernel <<<BL, 256, 0, stream>>>(zx, norm_w);
  gemm_kernel<2><<<256*6, 256, 0, stream>>>(zx, woutb, 1536, ZLD, DD, 6, nullptr, nullptr, nullptr, x, out);
}